// Round 3
// baseline (736.210 us; speedup 1.0000x reference)
//
#include <hip/hip_runtime.h>
#include <hip/hip_cooperative_groups.h>
#include <math.h>

namespace cg = cooperative_groups;

#define B    32
#define T    2048
#define H    1024
#define OUTD 256
#define NC   32     // t-chunks in flash phase (chunk = 64 rows)
#define KC1  16     // k-chunks for h_t partials (chunk = 64)

// One cooperative kernel, 7 phases separated by grid.sync().
// Grid target: 1024 blocks x 256 threads = 4 blocks/CU resident on 256 CUs.
// LDS: 4*H+8 floats = 16.1 KB/block (64.5 KB/CU at 4 blocks). VGPR capped 128.
__global__ __launch_bounds__(256, 4) void mega(
    const float* __restrict__ hs, const float* __restrict__ W1,
    const float* __restrict__ b1, const float* __restrict__ Wv,
    const float* __restrict__ bv, float* __restrict__ out,
    float* ws)
{
    cg::grid_group grid = cg::this_grid();
    const int bid = blockIdx.x;
    const int tid = threadIdx.x;
    const int gsz = gridDim.x;

    // workspace layout (same as 7-kernel version)
    float* ph    = ws;                              // KC1*B*H
    float* h_t   = ph + (size_t)KC1 * B * H;        // B*H
    float* u     = h_t + (size_t)B * H;             // B*H
    float* m_p   = u + (size_t)B * H;               // B*NC
    float* l_p   = m_p + B * NC;                    // B*NC
    float* ctx_p = l_p + B * NC;                    // B*NC*H
    float* pre   = ctx_p + (size_t)B * NC * H;      // B*2H
    float* accum = pre + (size_t)B * 2 * H;         // B*OUTD

    __shared__ float smem[4 * H + 8];               // reused by P1/P4/P6

    // ============ P1: h_t partials (64 jobs) + zero accum (job 64) ============
    for (int job = bid; job < 65; job += gsz) {
        if (job < 64) {
            const int hh = (job & 3) * 256 + tid;   // 4 h-tiles of 256
            const int k0 = (job >> 2) * 64;         // 16 k-chunks of 64
            float (*s_hs)[64] = (float (*)[64])smem;
            for (int it = 0; it < 8; ++it) {
                int idx = tid + it * 256;
                int b = idx >> 6, k = idx & 63;
                s_hs[b][k] = hs[((size_t)(b * T + (T - 1)) << 10) + k0 + k];
            }
            __syncthreads();
            float acc[B];
#pragma unroll
            for (int b = 0; b < B; ++b) acc[b] = 0.f;
            for (int k4 = 0; k4 < 16; ++k4) {
                float w0 = W1[(size_t)(k0 + k4 * 4 + 0) * H + hh];
                float w1 = W1[(size_t)(k0 + k4 * 4 + 1) * H + hh];
                float w2 = W1[(size_t)(k0 + k4 * 4 + 2) * H + hh];
                float w3 = W1[(size_t)(k0 + k4 * 4 + 3) * H + hh];
#pragma unroll
                for (int b = 0; b < B; ++b) {
                    const float4 hv = *(const float4*)&s_hs[b][k4 * 4];
                    acc[b] = fmaf(hv.x, w0, acc[b]);
                    acc[b] = fmaf(hv.y, w1, acc[b]);
                    acc[b] = fmaf(hv.z, w2, acc[b]);
                    acc[b] = fmaf(hv.w, w3, acc[b]);
                }
            }
            float* dst = ph + ((size_t)(job >> 2) * B << 10);
#pragma unroll
            for (int b = 0; b < B; ++b) dst[((size_t)b << 10) + hh] = acc[b];
            __syncthreads();   // protect smem if this block takes another job
        } else {
            for (int i = tid; i < B * OUTD; i += 256) accum[i] = 0.f;
        }
    }
    grid.sync();

    // ============ P2: h_t = sum(partials) + b1 (128 jobs) ============
    for (int job = bid; job < (B * H) / 256; job += gsz) {
        int i = job * 256 + tid;                    // i = b*H + h
        int h = i & (H - 1);
        float s = b1[h];
#pragma unroll
        for (int c = 0; c < KC1; ++c) s += ph[((size_t)c * B << 10) + i];
        h_t[i] = s;
    }
    grid.sync();

    // ============ P3: u[b,k] = dot(W1[k,:], h_t[b,:]) (256 jobs) ============
    for (int job = bid; job < H / 4; job += gsz) {
        const int wid  = tid >> 6;
        const int lane = tid & 63;
        const int k    = job * 4 + wid;
        const float4* wr = (const float4*)(W1 + ((size_t)k << 10));
        float4 wq[4];
#pragma unroll
        for (int j = 0; j < 4; ++j) wq[j] = wr[lane + 64 * j];
        for (int b = 0; b < B; ++b) {
            const float4* hr = (const float4*)(h_t + ((size_t)b << 10));
            float s = 0.f;
#pragma unroll
            for (int j = 0; j < 4; ++j) {
                float4 hv = hr[lane + 64 * j];
                s += wq[j].x * hv.x + wq[j].y * hv.y + wq[j].z * hv.z + wq[j].w * hv.w;
            }
#pragma unroll
            for (int off = 32; off; off >>= 1) s += __shfl_xor(s, off, 64);
            if (lane == 0) u[((size_t)b << 10) + k] = s;
        }
    }
    grid.sync();

    // ============ P4: fused score + online softmax + pooling (1024 jobs) ======
    for (int cc = bid; cc < B * NC; cc += gsz) {
        const int c    = cc & (NC - 1);
        const int b    = cc >> 5;
        const int w    = tid >> 6;
        const int lane = tid & 63;

        const float4* urow = (const float4*)(u + ((size_t)b << 10));
        float4 uq[4];
#pragma unroll
        for (int j = 0; j < 4; ++j) uq[j] = urow[lane + 64 * j];

        const int t0 = c * 64 + w * 16;
        const float4* xrow = (const float4*)(hs + ((size_t)(b * T + t0) << 10));

        float m = -INFINITY, lsum = 0.f;
        float4 acc[4];
#pragma unroll
        for (int j = 0; j < 4; ++j) acc[j] = make_float4(0.f, 0.f, 0.f, 0.f);

        float4 x[4], y[4];
#pragma unroll
        for (int j = 0; j < 4; ++j) x[j] = xrow[lane + 64 * j];

        for (int r = 0; r < 16; ++r) {
            const float4* nrow = xrow + 256;
            if (r < 15) {
#pragma unroll
                for (int j = 0; j < 4; ++j) y[j] = nrow[lane + 64 * j];
            }
            float s = 0.f;
#pragma unroll
            for (int j = 0; j < 4; ++j)
                s += x[j].x * uq[j].x + x[j].y * uq[j].y + x[j].z * uq[j].z + x[j].w * uq[j].w;
#pragma unroll
            for (int off = 32; off; off >>= 1) s += __shfl_xor(s, off, 64);

            float mn = fmaxf(m, s);
            float al = __expf(m - mn);
            float wt = __expf(s - mn);
            lsum = lsum * al + wt;
#pragma unroll
            for (int j = 0; j < 4; ++j) {
                acc[j].x = fmaf(acc[j].x, al, wt * x[j].x);
                acc[j].y = fmaf(acc[j].y, al, wt * x[j].y);
                acc[j].z = fmaf(acc[j].z, al, wt * x[j].z);
                acc[j].w = fmaf(acc[j].w, al, wt * x[j].w);
            }
            m = mn;
#pragma unroll
            for (int j = 0; j < 4; ++j) x[j] = y[j];
            xrow = nrow;
        }

        // combine 4 waves within block
        float* sm = smem + 4 * H;        // 4 floats
        float* sl = smem + 4 * H + 4;    // 4 floats
        float (*sacc)[H] = (float (*)[H])smem;   // 16 KB
        if (lane == 0) { sm[w] = m; sl[w] = lsum; }
        __syncthreads();
        const float mp  = fmaxf(fmaxf(sm[0], sm[1]), fmaxf(sm[2], sm[3]));
        const float alw = __expf(m - mp);
        float4* sa = (float4*)&sacc[w][0];
#pragma unroll
        for (int j = 0; j < 4; ++j) {
            float4 v;
            v.x = acc[j].x * alw; v.y = acc[j].y * alw;
            v.z = acc[j].z * alw; v.w = acc[j].w * alw;
            sa[lane + 64 * j] = v;
        }
        __syncthreads();
        float lp = 0.f;
#pragma unroll
        for (int ww = 0; ww < 4; ++ww) lp += sl[ww] * __expf(sm[ww] - mp);

        float* dst = ctx_p + (((size_t)b * NC + c) << 10);
#pragma unroll
        for (int i = 0; i < 4; ++i) {
            int h = tid + 256 * i;
            dst[h] = sacc[0][h] + sacc[1][h] + sacc[2][h] + sacc[3][h];
        }
        if (tid == 0) { m_p[b * NC + c] = mp; l_p[b * NC + c] = lp; }
        __syncthreads();   // protect smem for a possible next job
    }
    grid.sync();

    // ============ P5: combine chunk partials; pre = [ctx, h_t] (128 jobs) =====
    for (int job = bid; job < B * 4; job += gsz) {
        const int b = job >> 2;
        const int h = (job & 3) * 256 + tid;
        float M = -INFINITY;
#pragma unroll
        for (int c = 0; c < NC; ++c) M = fmaxf(M, m_p[b * NC + c]);
        float L = 0.f;
#pragma unroll
        for (int c = 0; c < NC; ++c) L += l_p[b * NC + c] * __expf(m_p[b * NC + c] - M);
        const float inv = 1.f / L;
        float s = 0.f;
#pragma unroll
        for (int c = 0; c < NC; ++c)
            s += ctx_p[(((size_t)b * NC + c) << 10) + h] * __expf(m_p[b * NC + c] - M);
        pre[((size_t)b << 11) + h] = s * inv;
        pre[((size_t)b << 11) + H + h] = h_t[((size_t)b << 10) + h];
    }
    grid.sync();

    // ============ P6: pre @ Wv, k-split + atomic accumulate (256 jobs) ========
    for (int job = bid; job < 8 * B; job += gsz) {
        const int kc = job & 7;
        const int b  = job >> 3;
        const int o  = tid;
        float* sp = smem;
        sp[o] = pre[((size_t)b << 11) + kc * 256 + o];
        __syncthreads();
        float acc = 0.f;
        const float* wv = Wv + (size_t)kc * 256 * OUTD + o;
#pragma unroll 8
        for (int k = 0; k < 256; ++k)
            acc = fmaf(sp[k], wv[(size_t)k * OUTD], acc);
        atomicAdd(&accum[b * OUTD + o], acc);
        __syncthreads();   // protect sp for a possible next job
    }
    grid.sync();

    // ============ P7: out = tanh(accum + bv) (32 jobs) ============
    for (int job = bid; job < (B * OUTD) / 256; job += gsz) {
        int i = job * 256 + tid;
        out[i] = tanhf(accum[i] + bv[i & (OUTD - 1)]);
    }
}

extern "C" void kernel_launch(void* const* d_in, const int* in_sizes, int n_in,
                              void* d_out, int out_size, void* d_ws, size_t ws_size,
                              hipStream_t stream)
{
    const float* hs = (const float*)d_in[0];
    const float* W1 = (const float*)d_in[1];
    const float* b1 = (const float*)d_in[2];
    const float* Wv = (const float*)d_in[3];
    const float* bv = (const float*)d_in[4];
    float* out = (float*)d_out;
    float* ws  = (float*)d_ws;

    // Resolve the co-resident grid once (queries only — graph-capture safe).
    static int coop_grid = 0;
    if (coop_grid == 0) {
        int dev = 0, ncu = 0, nb = 0;
        (void)hipGetDevice(&dev);
        (void)hipDeviceGetAttribute(&ncu, hipDeviceAttributeMultiprocessorCount, dev);
        (void)hipOccupancyMaxActiveBlocksPerMultiprocessor(&nb, mega, 256, 0);
        int g = nb * ncu;
        if (g <= 0 || g > 1024) g = 1024;  // design point: 4 blocks/CU x 256 CU
        coop_grid = g;
    }

    void* args[] = { (void*)&hs, (void*)&W1, (void*)&b1, (void*)&Wv,
                     (void*)&bv, (void*)&out, (void*)&ws };
    (void)hipLaunchCooperativeKernel(mega, dim3(coop_grid), dim3(256),
                                     args, 0, stream);
}

// Round 4
// 429.235 us; speedup vs baseline: 1.7152x; 1.7152x over previous
//
#include <hip/hip_runtime.h>
#include <math.h>

#define B   32
#define T   2048
#define H   1024
#define OUTD 256
#define NC  32     // t-chunks in fused kernel (chunk = 64 rows)
#define KC1 16     // k-chunks in k1a (chunk = 64)

// ---------------- k1a: partial h_t = hs[:, T-1, :] @ W1 (k-split partials) ----
__global__ __launch_bounds__(256) void k1a_partial_ht(
    const float* __restrict__ hs, const float* __restrict__ W1,
    float* __restrict__ ph)
{
    const int tid = threadIdx.x;
    const int h   = blockIdx.x * 256 + tid;   // 4 h-tiles
    const int k0  = blockIdx.y * 64;          // 16 k-chunks

    __shared__ float s_hs[B][64];
    for (int it = 0; it < 8; ++it) {
        int idx = tid + it * 256;
        int b = idx >> 6, k = idx & 63;
        s_hs[b][k] = hs[((size_t)(b * T + (T - 1)) << 10) + k0 + k];
    }
    __syncthreads();

    float acc[B];
#pragma unroll
    for (int b = 0; b < B; ++b) acc[b] = 0.f;

    for (int k4 = 0; k4 < 16; ++k4) {
        float w0 = W1[(size_t)(k0 + k4 * 4 + 0) * H + h];
        float w1 = W1[(size_t)(k0 + k4 * 4 + 1) * H + h];
        float w2 = W1[(size_t)(k0 + k4 * 4 + 2) * H + h];
        float w3 = W1[(size_t)(k0 + k4 * 4 + 3) * H + h];
#pragma unroll
        for (int b = 0; b < B; ++b) {
            const float4 hv = *(const float4*)&s_hs[b][k4 * 4];
            acc[b] = fmaf(hv.x, w0, acc[b]);
            acc[b] = fmaf(hv.y, w1, acc[b]);
            acc[b] = fmaf(hv.z, w2, acc[b]);
            acc[b] = fmaf(hv.w, w3, acc[b]);
        }
    }
    float* dst = ph + ((size_t)blockIdx.y * B << 10);
#pragma unroll
    for (int b = 0; b < B; ++b) dst[((size_t)b << 10) + h] = acc[b];
}

// ---------------- k1b: h_t = sum(partials) + b1; also zero accum -------------
__global__ __launch_bounds__(256) void k1b_reduce_ht(
    const float* __restrict__ ph, const float* __restrict__ b1,
    float* __restrict__ h_t, float* __restrict__ accum)
{
    int i = blockIdx.x * 256 + threadIdx.x;   // 0..B*H-1 (i = b*H + h)
    int h = i & (H - 1);
    float s = b1[h];
#pragma unroll
    for (int c = 0; c < KC1; ++c)
        s += ph[((size_t)c * B << 10) + i];
    h_t[i] = s;
    if (i < B * OUTD) accum[i] = 0.f;         // replaces hipMemsetAsync
}

// ---------------- k2: u[b,k] = dot(W1[k,:], h_t[b,:]) ------------------------
__global__ __launch_bounds__(256) void k2_compute_u(
    const float* __restrict__ W1, const float* __restrict__ h_t,
    float* __restrict__ u)
{
    const int wid  = threadIdx.x >> 6;
    const int lane = threadIdx.x & 63;
    const int k    = blockIdx.x * 4 + wid;    // 256 blocks x 4 waves = 1024 k
    const float4* wr = (const float4*)(W1 + ((size_t)k << 10));
    float4 wq[4];
#pragma unroll
    for (int j = 0; j < 4; ++j) wq[j] = wr[lane + 64 * j];

    for (int b = 0; b < B; ++b) {
        const float4* hr = (const float4*)(h_t + ((size_t)b << 10));
        float s = 0.f;
#pragma unroll
        for (int j = 0; j < 4; ++j) {
            float4 hv = hr[lane + 64 * j];
            s += wq[j].x * hv.x + wq[j].y * hv.y + wq[j].z * hv.z + wq[j].w * hv.w;
        }
#pragma unroll
        for (int off = 32; off; off >>= 1) s += __shfl_xor(s, off, 64);
        if (lane == 0) u[((size_t)b << 10) + k] = s;
    }
}

// ---------------- k3: fused score + online softmax + weighted pooling --------
__global__ __launch_bounds__(256) void k3_fused(
    const float* __restrict__ hs, const float* __restrict__ u,
    float* __restrict__ ctx_p, float* __restrict__ m_p, float* __restrict__ l_p)
{
    const int c    = blockIdx.x;          // t-chunk (0..31)
    const int b    = blockIdx.y;          // batch
    const int w    = threadIdx.x >> 6;    // wave 0..3
    const int lane = threadIdx.x & 63;
    const int tid  = threadIdx.x;

    const float4* urow = (const float4*)(u + ((size_t)b << 10));
    float4 uq[4];
#pragma unroll
    for (int j = 0; j < 4; ++j) uq[j] = urow[lane + 64 * j];

    const int t0 = c * 64 + w * 16;       // 16 rows per wave
    const float4* xrow = (const float4*)(hs + ((size_t)(b * T + t0) << 10));

    float m = -INFINITY, lsum = 0.f;
    float4 acc[4];
#pragma unroll
    for (int j = 0; j < 4; ++j) acc[j] = make_float4(0.f, 0.f, 0.f, 0.f);

    float4 x[4], y[4];
#pragma unroll
    for (int j = 0; j < 4; ++j) x[j] = xrow[lane + 64 * j];

    for (int r = 0; r < 16; ++r) {
        const float4* nrow = xrow + 256;
        if (r < 15) {
#pragma unroll
            for (int j = 0; j < 4; ++j) y[j] = nrow[lane + 64 * j];
        }
        float s = 0.f;
#pragma unroll
        for (int j = 0; j < 4; ++j)
            s += x[j].x * uq[j].x + x[j].y * uq[j].y + x[j].z * uq[j].z + x[j].w * uq[j].w;
#pragma unroll
        for (int off = 32; off; off >>= 1) s += __shfl_xor(s, off, 64);

        float mn = fmaxf(m, s);
        float al = __expf(m - mn);     // exp(-inf)=0 on first row
        float wt = __expf(s - mn);
        lsum = lsum * al + wt;
#pragma unroll
        for (int j = 0; j < 4; ++j) {
            acc[j].x = fmaf(acc[j].x, al, wt * x[j].x);
            acc[j].y = fmaf(acc[j].y, al, wt * x[j].y);
            acc[j].z = fmaf(acc[j].z, al, wt * x[j].z);
            acc[j].w = fmaf(acc[j].w, al, wt * x[j].w);
        }
        m = mn;
#pragma unroll
        for (int j = 0; j < 4; ++j) x[j] = y[j];
        xrow = nrow;
    }

    // ---- combine 4 waves within block ----
    __shared__ float sm[4], sl[4];
    __shared__ float sacc[4][H];          // 16 KB
    if (lane == 0) { sm[w] = m; sl[w] = lsum; }
    __syncthreads();
    const float mp = fmaxf(fmaxf(sm[0], sm[1]), fmaxf(sm[2], sm[3]));
    const float alw = __expf(m - mp);
    float4* sa = (float4*)&sacc[w][0];
#pragma unroll
    for (int j = 0; j < 4; ++j) {
        float4 v;
        v.x = acc[j].x * alw; v.y = acc[j].y * alw;
        v.z = acc[j].z * alw; v.w = acc[j].w * alw;
        sa[lane + 64 * j] = v;
    }
    __syncthreads();
    float lp = 0.f;
#pragma unroll
    for (int ww = 0; ww < 4; ++ww) lp += sl[ww] * __expf(sm[ww] - mp);

    float* dst = ctx_p + (((size_t)b * NC + c) << 10);
#pragma unroll
    for (int i = 0; i < 4; ++i) {
        int h = tid + 256 * i;
        dst[h] = sacc[0][h] + sacc[1][h] + sacc[2][h] + sacc[3][h];
    }
    if (tid == 0) { m_p[b * NC + c] = mp; l_p[b * NC + c] = lp; }
}

// ---------------- k45: fused chunk-combine + pre-slice + matmul + atomic -----
// One block per (kc, b). Builds its own 256-float slice of pre = [ctx, h_t]
// in LDS (kc<4: softmax-combined context; kc>=4: h_t copy), then multiplies
// against Wv's 256-row chunk and atomically accumulates into accum.
__global__ __launch_bounds__(256) void k45_matmul(
    const float* __restrict__ ctx_p, const float* __restrict__ m_p,
    const float* __restrict__ l_p, const float* __restrict__ h_t,
    const float* __restrict__ Wv, float* __restrict__ accum)
{
    const int kc = blockIdx.x;   // 0..7 (k-chunk of 256)
    const int b  = blockIdx.y;
    const int o  = threadIdx.x;

    __shared__ float sp[256];
    if (kc < 4) {
        // softmax-combine across the 32 t-chunks for this 256-wide h-slice
        float M = -INFINITY;
#pragma unroll
        for (int c = 0; c < NC; ++c) M = fmaxf(M, m_p[b * NC + c]);
        float L = 0.f;
#pragma unroll
        for (int c = 0; c < NC; ++c) L += l_p[b * NC + c] * __expf(m_p[b * NC + c] - M);
        float s = 0.f;
#pragma unroll
        for (int c = 0; c < NC; ++c)
            s += ctx_p[(((size_t)b * NC + c) << 10) + kc * 256 + o]
                 * __expf(m_p[b * NC + c] - M);
        sp[o] = s / L;
    } else {
        sp[o] = h_t[((size_t)b << 10) + (kc - 4) * 256 + o];
    }
    __syncthreads();

    float acc = 0.f;
    const float* wv = Wv + (size_t)kc * 256 * OUTD + o;
#pragma unroll 8
    for (int k = 0; k < 256; ++k)
        acc = fmaf(sp[k], wv[(size_t)k * OUTD], acc);
    atomicAdd(&accum[b * OUTD + o], acc);
}

// ---------------- k5b: out = tanh(accum + bv) --------------------------------
__global__ __launch_bounds__(256) void k5b_tanh(
    const float* __restrict__ accum, const float* __restrict__ bv,
    float* __restrict__ out)
{
    int i = blockIdx.x * 256 + threadIdx.x;
    out[i] = tanhf(accum[i] + bv[i & (OUTD - 1)]);
}

extern "C" void kernel_launch(void* const* d_in, const int* in_sizes, int n_in,
                              void* d_out, int out_size, void* d_ws, size_t ws_size,
                              hipStream_t stream)
{
    const float* hs = (const float*)d_in[0];
    const float* W1 = (const float*)d_in[1];
    const float* b1 = (const float*)d_in[2];
    const float* Wv = (const float*)d_in[3];
    const float* bv = (const float*)d_in[4];
    float* out = (float*)d_out;
    float* ws  = (float*)d_ws;

    float* ph    = ws;                              // KC1*B*H  = 524288 floats
    float* h_t   = ph + (size_t)KC1 * B * H;        // B*H      = 32768
    float* u     = h_t + (size_t)B * H;             // B*H      = 32768
    float* m_p   = u + (size_t)B * H;               // B*NC     = 1024
    float* l_p   = m_p + B * NC;                    // B*NC     = 1024
    float* ctx_p = l_p + B * NC;                    // B*NC*H   = 1048576
    float* accum = ctx_p + (size_t)B * NC * H;      // B*OUTD   = 8192
    // total ~6.6 MB of d_ws

    k1a_partial_ht<<<dim3(4, KC1), 256, 0, stream>>>(hs, W1, ph);
    k1b_reduce_ht<<<(B * H) / 256, 256, 0, stream>>>(ph, b1, h_t, accum);
    k2_compute_u<<<H / 4, 256, 0, stream>>>(W1, h_t, u);
    k3_fused<<<dim3(NC, B), 256, 0, stream>>>(hs, u, ctx_p, m_p, l_p);
    k45_matmul<<<dim3(8, B), 256, 0, stream>>>(ctx_p, m_p, l_p, h_t, Wv, accum);
    k5b_tanh<<<B, 256, 0, stream>>>(accum, bv, out);
}